// Round 1
// baseline (247.988 us; speedup 1.0000x reference)
//
#include <hip/hip_runtime.h>
#include <math.h>

// Problem constants
#define B_  2
#define L_  225
#define D_  256
#define H_  4
#define DH_ 64
#define BH_ (B_*H_)
#define M_  (B_*L_)        // 450
#define LL_ (L_*L_)        // 50625
#define RHO 0.1f
#define INV_D 0.015625f    // 1/64
#define INV_L (1.0f/225.0f)
#define INV_SQRT_D 0.125f  // 1/sqrt(64)

// ---------------------------------------------------------------------------
// K1: q/k/v = x @ W^T, written directly in [B,H,L,d] layout.
// grid (ceil(450/32)=15, 256/32=8, 3), block 256
__global__ __launch_bounds__(256) void k_qkv(
    const float* __restrict__ x, const float* __restrict__ Wq,
    const float* __restrict__ Wk, const float* __restrict__ Wv,
    float* __restrict__ q, float* __restrict__ k, float* __restrict__ v)
{
    const int which = blockIdx.z;
    const float* W = (which == 0) ? Wq : (which == 1) ? Wk : Wv;
    float* out = (which == 0) ? q : (which == 1) ? k : v;
    const int m0 = blockIdx.x * 32;
    const int n0 = blockIdx.y * 32;
    __shared__ float Xs[32][33];
    __shared__ float Ws[32][33];
    const int t = threadIdx.x;
    const int ty = t >> 4, tx = t & 15;
    float acc[2][2] = {};
    for (int kt = 0; kt < D_; kt += 32) {
        #pragma unroll
        for (int i = 0; i < 4; ++i) {
            int li = t + i * 256;
            int r = li >> 5, c = li & 31;
            int m = m0 + r;
            Xs[r][c] = (m < M_) ? x[m * D_ + kt + c] : 0.f;
            Ws[r][c] = W[(n0 + r) * D_ + kt + c];
        }
        __syncthreads();
        #pragma unroll
        for (int kk = 0; kk < 32; ++kk) {
            float a0 = Xs[ty*2+0][kk], a1 = Xs[ty*2+1][kk];
            float b0 = Ws[tx*2+0][kk], b1 = Ws[tx*2+1][kk];
            acc[0][0] += a0*b0; acc[0][1] += a0*b1;
            acc[1][0] += a1*b0; acc[1][1] += a1*b1;
        }
        __syncthreads();
    }
    #pragma unroll
    for (int i = 0; i < 2; ++i) {
        int m = m0 + ty*2 + i;
        if (m >= M_) continue;
        int b = m / L_, l = m % L_;
        #pragma unroll
        for (int j = 0; j < 2; ++j) {
            int n = n0 + tx*2 + j;
            int h = n >> 6, dd = n & 63;
            out[((b * H_ + h) * L_ + l) * DH_ + dd] = acc[i][j];
        }
    }
}

// ---------------------------------------------------------------------------
// K2: S[bh] = q[bh] @ k[bh]^T  (K=64). grid (8,8,8), block 256
__global__ __launch_bounds__(256) void k_scores(
    const float* __restrict__ q, const float* __restrict__ kk_,
    float* __restrict__ S)
{
    const int bh = blockIdx.z;
    const int i0 = blockIdx.x * 32, j0 = blockIdx.y * 32;
    __shared__ float Qs[32][65], Ks[32][65];
    const float* qb = q + bh * L_ * DH_;
    const float* kb = kk_ + bh * L_ * DH_;
    const int t = threadIdx.x;
    #pragma unroll
    for (int i = 0; i < 8; ++i) {
        int li = t + i * 256;
        int r = li >> 6, c = li & 63;
        Qs[r][c] = (i0 + r < L_) ? qb[(i0 + r) * DH_ + c] : 0.f;
        Ks[r][c] = (j0 + r < L_) ? kb[(j0 + r) * DH_ + c] : 0.f;
    }
    __syncthreads();
    const int ty = t >> 4, tx = t & 15;
    float acc[2][2] = {};
    #pragma unroll
    for (int c = 0; c < 64; ++c) {
        float a0 = Qs[ty*2+0][c], a1 = Qs[ty*2+1][c];
        float b0 = Ks[tx*2+0][c], b1 = Ks[tx*2+1][c];
        acc[0][0] += a0*b0; acc[0][1] += a0*b1;
        acc[1][0] += a1*b0; acc[1][1] += a1*b1;
    }
    float* Sb = S + bh * LL_;
    #pragma unroll
    for (int i = 0; i < 2; ++i) {
        int gi = i0 + ty*2 + i;
        if (gi >= L_) continue;
        #pragma unroll
        for (int j = 0; j < 2; ++j) {
            int gj = j0 + tx*2 + j;
            if (gj < L_) Sb[gi * L_ + gj] = acc[i][j];
        }
    }
}

// ---------------------------------------------------------------------------
// K3: the O(L^3) adjacency build.
// A[i,k] = (1/L) * sum_j thresh(S[i,j]*S[k,j]/d), diag(i==k)=0.
// grid (8,8,8), block 256; each thread computes 1x4 outputs.
__global__ __launch_bounds__(256) void k_adj(
    const float* __restrict__ S, float* __restrict__ A)
{
    const int bh = blockIdx.z;
    const int i0 = blockIdx.x * 32, k0 = blockIdx.y * 32;
    __shared__ float Si[32][65], Sk[32][65];
    const float* Sb = S + bh * LL_;
    const int t = threadIdx.x;
    const int ii = t & 31, kk0 = (t >> 5) * 4;
    float acc[4] = {};
    for (int jc = 0; jc < L_; jc += 64) {
        #pragma unroll
        for (int i = 0; i < 8; ++i) {
            int li = t + i * 256;
            int r = li >> 6, c = li & 63;
            int j = jc + c;
            Si[r][c] = (i0 + r < L_ && j < L_) ? Sb[(i0 + r) * L_ + j] : 0.f;
            Sk[r][c] = (k0 + r < L_ && j < L_) ? Sb[(k0 + r) * L_ + j] : 0.f;
        }
        __syncthreads();
        #pragma unroll 8
        for (int j = 0; j < 64; ++j) {
            float si = Si[ii][j];
            #pragma unroll
            for (int c = 0; c < 4; ++c) {
                float u = si * Sk[kk0 + c][j] * INV_D;
                acc[c] += (u > RHO) ? u : 0.f;
            }
        }
        __syncthreads();
    }
    int gi = i0 + ii;
    if (gi < L_) {
        float* Ab = A + bh * LL_ + gi * L_;
        #pragma unroll
        for (int c = 0; c < 4; ++c) {
            int gk = k0 + kk0 + c;
            if (gk < L_) Ab[gk] = (gi == gk) ? 0.f : acc[c] * INV_L;
        }
    }
}

// ---------------------------------------------------------------------------
// K4a: dinv[bh,i] = 1/sqrt(max(1 + sum_k A[i,k], 1e-6)). grid (8), block 256
__global__ __launch_bounds__(256) void k_dinv(
    const float* __restrict__ A, float* __restrict__ dinv)
{
    int bh = blockIdx.x;
    int i = threadIdx.x;
    if (i >= L_) return;
    const float* Ab = A + bh * LL_ + i * L_;
    float s = 1.0f;  // the +I diagonal
    for (int kx = 0; kx < L_; ++kx) s += Ab[kx];
    s = fmaxf(s, 1e-6f);
    dinv[bh * L_ + i] = 1.0f / sqrtf(s);
}

// ---------------------------------------------------------------------------
// K4b: Ahat = dinv_r * (A + I) * dinv_c, elementwise. grid ceil(405000/256)
__global__ __launch_bounds__(256) void k_ahat(
    const float* __restrict__ A, const float* __restrict__ dinv,
    float* __restrict__ Ahat)
{
    int e = blockIdx.x * 256 + threadIdx.x;
    if (e >= BH_ * LL_) return;
    int bh = e / LL_;
    int rem = e - bh * LL_;
    int r = rem / L_;
    int c = rem - r * L_;
    float val = A[e] + ((r == c) ? 1.f : 0.f);
    Ahat[e] = val * dinv[bh * L_ + r] * dinv[bh * L_ + c];
}

// ---------------------------------------------------------------------------
// K5: M1 = Ahat @ S (no transpose). grid (8,8,8), block 256
__global__ __launch_bounds__(256) void k_m1(
    const float* __restrict__ Ahat, const float* __restrict__ S,
    float* __restrict__ M1)
{
    const int bh = blockIdx.z;
    const int i0 = blockIdx.x * 32, c0 = blockIdx.y * 32;
    __shared__ float As[32][33], Bs[32][33];
    const float* Ab = Ahat + bh * LL_;
    const float* Sb = S + bh * LL_;
    const int t = threadIdx.x;
    const int ty = t >> 4, tx = t & 15;
    float acc[2][2] = {};
    for (int jt = 0; jt < L_; jt += 32) {
        #pragma unroll
        for (int i = 0; i < 4; ++i) {
            int li = t + i * 256;
            int r = li >> 5, c = li & 31;
            As[r][c] = (i0 + r < L_ && jt + c < L_) ? Ab[(i0 + r) * L_ + jt + c] : 0.f;
            Bs[r][c] = (jt + r < L_ && c0 + c < L_) ? Sb[(jt + r) * L_ + c0 + c] : 0.f;
        }
        __syncthreads();
        #pragma unroll
        for (int kk = 0; kk < 32; ++kk) {
            float a0 = As[ty*2+0][kk], a1 = As[ty*2+1][kk];
            float b0 = Bs[kk][tx*2+0], b1 = Bs[kk][tx*2+1];
            acc[0][0] += a0*b0; acc[0][1] += a0*b1;
            acc[1][0] += a1*b0; acc[1][1] += a1*b1;
        }
        __syncthreads();
    }
    float* Mb = M1 + bh * LL_;
    #pragma unroll
    for (int i = 0; i < 2; ++i) {
        int gi = i0 + ty*2 + i;
        if (gi >= L_) continue;
        #pragma unroll
        for (int j = 0; j < 2; ++j) {
            int gc = c0 + tx*2 + j;
            if (gc < L_) Mb[gi * L_ + gc] = acc[i][j];
        }
    }
}

// ---------------------------------------------------------------------------
// K6a: sjump = (M1 @ Ahat^T) / sqrt(d), stored into attn buffer. grid (8,8,8)
__global__ __launch_bounds__(256) void k_sjump(
    const float* __restrict__ M1, const float* __restrict__ Ahat,
    float* __restrict__ attn)
{
    const int bh = blockIdx.z;
    const int i0 = blockIdx.x * 32, l0 = blockIdx.y * 32;
    __shared__ float As[32][33], Bs[32][33];
    const float* Mb = M1 + bh * LL_;
    const float* Ab = Ahat + bh * LL_;
    const int t = threadIdx.x;
    const int ty = t >> 4, tx = t & 15;
    float acc[2][2] = {};
    for (int jt = 0; jt < L_; jt += 32) {
        #pragma unroll
        for (int i = 0; i < 4; ++i) {
            int li = t + i * 256;
            int r = li >> 5, c = li & 31;
            As[r][c] = (i0 + r < L_ && jt + c < L_) ? Mb[(i0 + r) * L_ + jt + c] : 0.f;
            Bs[r][c] = (l0 + r < L_ && jt + c < L_) ? Ab[(l0 + r) * L_ + jt + c] : 0.f;
        }
        __syncthreads();
        #pragma unroll
        for (int kk = 0; kk < 32; ++kk) {
            float a0 = As[ty*2+0][kk], a1 = As[ty*2+1][kk];
            float b0 = Bs[tx*2+0][kk], b1 = Bs[tx*2+1][kk];
            acc[0][0] += a0*b0; acc[0][1] += a0*b1;
            acc[1][0] += a1*b0; acc[1][1] += a1*b1;
        }
        __syncthreads();
    }
    float* ob = attn + bh * LL_;
    #pragma unroll
    for (int i = 0; i < 2; ++i) {
        int gi = i0 + ty*2 + i;
        if (gi >= L_) continue;
        #pragma unroll
        for (int j = 0; j < 2; ++j) {
            int gl = l0 + tx*2 + j;
            if (gl < L_) ob[gi * L_ + gl] = acc[i][j] * INV_SQRT_D;
        }
    }
}

// ---------------------------------------------------------------------------
// K6b: row softmax in-place on attn. grid (225, 8), block 256
__global__ __launch_bounds__(256) void k_softmax(float* __restrict__ attn)
{
    const int bh = blockIdx.y, i = blockIdx.x;
    float* row = attn + bh * LL_ + i * L_;
    const int t = threadIdx.x;
    __shared__ float red[256];
    float v = (t < L_) ? row[t] : -INFINITY;
    red[t] = v;
    __syncthreads();
    for (int s = 128; s > 0; s >>= 1) {
        if (t < s) red[t] = fmaxf(red[t], red[t + s]);
        __syncthreads();
    }
    float m = red[0];
    __syncthreads();
    float e = (t < L_) ? expf(v - m) : 0.f;
    red[t] = e;
    __syncthreads();
    for (int s = 128; s > 0; s >>= 1) {
        if (t < s) red[t] += red[t + s];
        __syncthreads();
    }
    float inv = 1.0f / red[0];
    if (t < L_) row[t] = e * inv;
}

// ---------------------------------------------------------------------------
// K7: out_heads = attn @ v, written into [B,L,H*d] merged layout.
// grid (8 i-tiles, 8 bh), block 256; thread = (dd, 8 rows)
__global__ __launch_bounds__(256) void k_av(
    const float* __restrict__ attn, const float* __restrict__ v,
    float* __restrict__ oh)
{
    const int bh = blockIdx.y, i0 = blockIdx.x * 32;
    __shared__ float As[32][33];
    __shared__ float Vs[32][64];
    const float* ab = attn + bh * LL_;
    const float* vb = v + bh * L_ * DH_;
    const int t = threadIdx.x;
    const int dd = t & 63, iy0 = (t >> 6) * 8;
    float acc[8] = {};
    for (int lc = 0; lc < L_; lc += 32) {
        #pragma unroll
        for (int x2 = 0; x2 < 4; ++x2) {
            int li = t + x2 * 256;
            int r = li >> 5, c = li & 31;
            As[r][c] = (i0 + r < L_ && lc + c < L_) ? ab[(i0 + r) * L_ + lc + c] : 0.f;
        }
        #pragma unroll
        for (int x2 = 0; x2 < 8; ++x2) {
            int li = t + x2 * 256;
            int r = li >> 6, c = li & 63;
            Vs[r][c] = (lc + r < L_) ? vb[(lc + r) * DH_ + c] : 0.f;
        }
        __syncthreads();
        #pragma unroll
        for (int ll = 0; ll < 32; ++ll) {
            float vv = Vs[ll][dd];
            #pragma unroll
            for (int r = 0; r < 8; ++r) acc[r] += As[iy0 + r][ll] * vv;
        }
        __syncthreads();
    }
    const int b = bh >> 2, h = bh & 3;
    #pragma unroll
    for (int r = 0; r < 8; ++r) {
        int i = i0 + iy0 + r;
        if (i < L_) oh[(b * L_ + i) * (H_ * DH_) + h * DH_ + dd] = acc[r];
    }
}

// ---------------------------------------------------------------------------
// K8: final = out_heads @ Wo^T. grid (15,8), block 256
__global__ __launch_bounds__(256) void k_out(
    const float* __restrict__ oh, const float* __restrict__ Wo,
    float* __restrict__ out)
{
    const int m0 = blockIdx.x * 32;
    const int n0 = blockIdx.y * 32;
    __shared__ float Xs[32][33];
    __shared__ float Ws[32][33];
    const int t = threadIdx.x;
    const int ty = t >> 4, tx = t & 15;
    float acc[2][2] = {};
    for (int kt = 0; kt < D_; kt += 32) {
        #pragma unroll
        for (int i = 0; i < 4; ++i) {
            int li = t + i * 256;
            int r = li >> 5, c = li & 31;
            int m = m0 + r;
            Xs[r][c] = (m < M_) ? oh[m * D_ + kt + c] : 0.f;
            Ws[r][c] = Wo[(n0 + r) * D_ + kt + c];
        }
        __syncthreads();
        #pragma unroll
        for (int kk = 0; kk < 32; ++kk) {
            float a0 = Xs[ty*2+0][kk], a1 = Xs[ty*2+1][kk];
            float b0 = Ws[tx*2+0][kk], b1 = Ws[tx*2+1][kk];
            acc[0][0] += a0*b0; acc[0][1] += a0*b1;
            acc[1][0] += a1*b0; acc[1][1] += a1*b1;
        }
        __syncthreads();
    }
    #pragma unroll
    for (int i = 0; i < 2; ++i) {
        int m = m0 + ty*2 + i;
        if (m >= M_) continue;
        #pragma unroll
        for (int j = 0; j < 2; ++j) {
            int n = n0 + tx*2 + j;
            out[m * D_ + n] = acc[i][j];
        }
    }
}

// ---------------------------------------------------------------------------
extern "C" void kernel_launch(void* const* d_in, const int* in_sizes, int n_in,
                              void* d_out, int out_size, void* d_ws, size_t ws_size,
                              hipStream_t stream)
{
    const float* x  = (const float*)d_in[0];
    const float* Wq = (const float*)d_in[1];
    const float* Wk = (const float*)d_in[2];
    const float* Wv = (const float*)d_in[3];
    const float* Wo = (const float*)d_in[4];
    float* out = (float*)d_out;

    // Workspace layout (floats)
    float* ws   = (float*)d_ws;
    float* q    = ws;                  // 115200
    float* k    = q    + B_*H_*L_*DH_; // 115200
    float* v    = k    + B_*H_*L_*DH_; // 115200
    float* S    = v    + B_*H_*L_*DH_; // 405000
    float* A    = S    + BH_*LL_;      // 405000
    float* Ahat = A    + BH_*LL_;      // 405000
    float* M1   = Ahat + BH_*LL_;      // 405000
    float* attn = M1   + BH_*LL_;      // 405000
    float* dinv = attn + BH_*LL_;      // 1800
    float* oh   = dinv + BH_*L_;       // 115200
    // total ~9.95 MB

    dim3 blk(256);
    dim3 g1((M_ + 31) / 32, D_ / 32, 3);
    k_qkv<<<g1, blk, 0, stream>>>(x, Wq, Wk, Wv, q, k, v);

    dim3 g2(8, 8, BH_);
    k_scores<<<g2, blk, 0, stream>>>(q, k, S);

    dim3 g3(8, 8, BH_);
    k_adj<<<g3, blk, 0, stream>>>(S, A);

    k_dinv<<<dim3(BH_), blk, 0, stream>>>(A, dinv);

    k_ahat<<<dim3((BH_ * LL_ + 255) / 256), blk, 0, stream>>>(A, dinv, Ahat);

    dim3 g5(8, 8, BH_);
    k_m1<<<g5, blk, 0, stream>>>(Ahat, S, M1);

    dim3 g6(8, 8, BH_);
    k_sjump<<<g6, blk, 0, stream>>>(M1, Ahat, attn);

    dim3 g6b(L_, BH_);
    k_softmax<<<g6b, blk, 0, stream>>>(attn);

    dim3 g7(8, BH_);
    k_av<<<g7, blk, 0, stream>>>(attn, v, oh);

    dim3 g8((M_ + 31) / 32, D_ / 32);
    k_out<<<g8, blk, 0, stream>>>(oh, Wo, out);
}

// Round 2
// 198.983 us; speedup vs baseline: 1.2463x; 1.2463x over previous
//
#include <hip/hip_runtime.h>
#include <math.h>

// Problem constants
#define B_  2
#define L_  225
#define D_  256
#define H_  4
#define DH_ 64
#define BH_ (B_*H_)
#define M_  (B_*L_)        // 450
#define LL_ (L_*L_)        // 50625
#define RHO 0.1f
#define INV_L (1.0f/225.0f)
#define INV_SQRT_D 0.125f  // 1/sqrt(64)

__device__ __forceinline__ float dinv_of(const float* deg, int idx) {
    return 1.0f / sqrtf(fmaxf(deg[idx], 1e-6f));
}

// ---------------------------------------------------------------------------
// K1: q/k/v = x @ W^T, written directly in [B,H,L,d] layout. Also inits deg=1.
// grid (15, 8, 3), block 256
__global__ __launch_bounds__(256) void k_qkv(
    const float* __restrict__ x, const float* __restrict__ Wq,
    const float* __restrict__ Wk, const float* __restrict__ Wv,
    float* __restrict__ q, float* __restrict__ k, float* __restrict__ v,
    float* __restrict__ deg)
{
    const int t = threadIdx.x;
    // deg init (the +I term): 15 blocks with (y==0,z==0) cover 1800 entries
    if (blockIdx.z == 0 && blockIdx.y == 0 && t < 128) {
        int idx = blockIdx.x * 128 + t;
        if (idx < BH_ * L_) deg[idx] = 1.0f;
    }
    const int which = blockIdx.z;
    const float* W = (which == 0) ? Wq : (which == 1) ? Wk : Wv;
    float* out = (which == 0) ? q : (which == 1) ? k : v;
    const int m0 = blockIdx.x * 32;
    const int n0 = blockIdx.y * 32;
    __shared__ float Xs[32][36];
    __shared__ float Ws[32][36];
    const int ty = t >> 4, tx = t & 15;
    const int sr = t >> 3, sc4 = (t & 7) * 4;
    float acc[2][2] = {};
    for (int kt = 0; kt < D_; kt += 32) {
        int m = m0 + sr;
        float4 xv = (m < M_) ? *(const float4*)&x[m * D_ + kt + sc4]
                             : make_float4(0.f, 0.f, 0.f, 0.f);
        float4 wv = *(const float4*)&W[(n0 + sr) * D_ + kt + sc4];
        *(float4*)&Xs[sr][sc4] = xv;
        *(float4*)&Ws[sr][sc4] = wv;
        __syncthreads();
        #pragma unroll
        for (int kk = 0; kk < 32; ++kk) {
            float a0 = Xs[ty*2+0][kk], a1 = Xs[ty*2+1][kk];
            float b0 = Ws[tx*2+0][kk], b1 = Ws[tx*2+1][kk];
            acc[0][0] += a0*b0; acc[0][1] += a0*b1;
            acc[1][0] += a1*b0; acc[1][1] += a1*b1;
        }
        __syncthreads();
    }
    #pragma unroll
    for (int i = 0; i < 2; ++i) {
        int m = m0 + ty*2 + i;
        if (m >= M_) continue;
        int b = m / L_, l = m % L_;
        #pragma unroll
        for (int j = 0; j < 2; ++j) {
            int n = n0 + tx*2 + j;
            int h = n >> 6, dd = n & 63;
            out[((b * H_ + h) * L_ + l) * DH_ + dd] = acc[i][j];
        }
    }
}

// ---------------------------------------------------------------------------
// K2: S[bh] = q[bh] @ k[bh]^T  (K=64). grid (8,8,8), block 256
__global__ __launch_bounds__(256) void k_scores(
    const float* __restrict__ q, const float* __restrict__ kk_,
    float* __restrict__ S)
{
    const int bh = blockIdx.z;
    const int i0 = blockIdx.x * 32, j0 = blockIdx.y * 32;
    __shared__ float Qs[32][68], Ks[32][68];
    const float* qb = q + bh * L_ * DH_;
    const float* kb = kk_ + bh * L_ * DH_;
    const int t = threadIdx.x;
    #pragma unroll
    for (int s = 0; s < 2; ++s) {
        int li = t + s * 256;
        int r = li >> 4, c4 = (li & 15) * 4;
        float4 qv = (i0 + r < L_) ? *(const float4*)&qb[(i0 + r) * DH_ + c4]
                                  : make_float4(0.f,0.f,0.f,0.f);
        float4 kv = (j0 + r < L_) ? *(const float4*)&kb[(j0 + r) * DH_ + c4]
                                  : make_float4(0.f,0.f,0.f,0.f);
        *(float4*)&Qs[r][c4] = qv;
        *(float4*)&Ks[r][c4] = kv;
    }
    __syncthreads();
    const int ty = t >> 4, tx = t & 15;
    float acc[2][2] = {};
    #pragma unroll
    for (int c = 0; c < 64; ++c) {
        float a0 = Qs[ty*2+0][c], a1 = Qs[ty*2+1][c];
        float b0 = Ks[tx*2+0][c], b1 = Ks[tx*2+1][c];
        acc[0][0] += a0*b0; acc[0][1] += a0*b1;
        acc[1][0] += a1*b0; acc[1][1] += a1*b1;
    }
    float* Sb = S + bh * LL_;
    #pragma unroll
    for (int i = 0; i < 2; ++i) {
        int gi = i0 + ty*2 + i;
        if (gi >= L_) continue;
        #pragma unroll
        for (int j = 0; j < 2; ++j) {
            int gj = j0 + tx*2 + j;
            if (gj < L_) Sb[gi * L_ + gj] = acc[i][j];
        }
    }
}

// ---------------------------------------------------------------------------
// K3: adjacency + degree accumulation.
// A[i,k] = (1/L) * sum_j thresh((S[i,j]/8)*(S[k,j]/8)), diag=0.
// deg[bh,i] += row-sum (atomics onto 1.0 init).
// grid (8,8,8), block 256; 2x2 outputs/thread, transposed pre-scaled tiles.
__global__ __launch_bounds__(256) void k_adj(
    const float* __restrict__ S, float* __restrict__ A, float* __restrict__ deg)
{
    const int bh = blockIdx.z;
    const int i0 = blockIdx.x * 32, k0 = blockIdx.y * 32;
    __shared__ float SiT[32][34], SkT[32][34];  // [j][row], pre-scaled by 1/8
    const float* Sb = S + bh * LL_;
    const int t = threadIdx.x;
    const int tx = t & 15, ty = t >> 4;
    float a00 = 0.f, a01 = 0.f, a10 = 0.f, a11 = 0.f;
    for (int jc = 0; jc < L_; jc += 32) {
        #pragma unroll
        for (int s = 0; s < 4; ++s) {
            int li = t + s * 256;
            int r = li >> 5, c = li & 31;
            int j = jc + c;
            SiT[c][r] = (i0 + r < L_ && j < L_) ? Sb[(i0 + r) * L_ + j] * 0.125f : 0.f;
            SkT[c][r] = (k0 + r < L_ && j < L_) ? Sb[(k0 + r) * L_ + j] * 0.125f : 0.f;
        }
        __syncthreads();
        #pragma unroll
        for (int j = 0; j < 32; ++j) {
            float2 a = *(const float2*)&SiT[j][ty * 2];
            float2 b = *(const float2*)&SkT[j][tx * 2];
            float u;
            u = a.x * b.x; a00 += (u > RHO) ? u : 0.f;
            u = a.x * b.y; a01 += (u > RHO) ? u : 0.f;
            u = a.y * b.x; a10 += (u > RHO) ? u : 0.f;
            u = a.y * b.y; a11 += (u > RHO) ? u : 0.f;
        }
        __syncthreads();
    }
    const int gi0 = i0 + ty * 2, gk0 = k0 + tx * 2;
    float v00 = (gi0     < L_ && gk0     < L_ && gi0     != gk0    ) ? a00 * INV_L : 0.f;
    float v01 = (gi0     < L_ && gk0 + 1 < L_ && gi0     != gk0 + 1) ? a01 * INV_L : 0.f;
    float v10 = (gi0 + 1 < L_ && gk0     < L_ && gi0 + 1 != gk0    ) ? a10 * INV_L : 0.f;
    float v11 = (gi0 + 1 < L_ && gk0 + 1 < L_ && gi0 + 1 != gk0 + 1) ? a11 * INV_L : 0.f;
    float* Ab = A + bh * LL_;
    if (gi0 < L_) {
        if (gk0     < L_) Ab[gi0 * L_ + gk0    ] = v00;
        if (gk0 + 1 < L_) Ab[gi0 * L_ + gk0 + 1] = v01;
    }
    if (gi0 + 1 < L_) {
        if (gk0     < L_) Ab[(gi0+1) * L_ + gk0    ] = v10;
        if (gk0 + 1 < L_) Ab[(gi0+1) * L_ + gk0 + 1] = v11;
    }
    // per-row partial degree: reduce over the 16 tx lanes (contiguous in wave)
    float rs0 = v00 + v01, rs1 = v10 + v11;
    #pragma unroll
    for (int m = 1; m < 16; m <<= 1) {
        rs0 += __shfl_xor(rs0, m);
        rs1 += __shfl_xor(rs1, m);
    }
    if (tx == 0) {
        if (gi0     < L_) atomicAdd(&deg[bh * L_ + gi0    ], rs0);
        if (gi0 + 1 < L_) atomicAdd(&deg[bh * L_ + gi0 + 1], rs1);
    }
}

// ---------------------------------------------------------------------------
// K4: M1 = dinv_i * (A+I) * dinv_j @ S   (Ahat folded in). grid (8,8,8)
__global__ __launch_bounds__(256) void k_m1(
    const float* __restrict__ A, const float* __restrict__ S,
    const float* __restrict__ deg, float* __restrict__ M1)
{
    const int bh = blockIdx.z;
    const int i0 = blockIdx.x * 32, c0 = blockIdx.y * 32;
    __shared__ float As[32][33];   // (A+I)[i0+r][jt+j]
    __shared__ float Ss[32][34];   // S[jt+j][c0+c] * dinv_j
    const float* Ab = A + bh * LL_;
    const float* Sb = S + bh * LL_;
    const float* db = deg + bh * L_;
    const int t = threadIdx.x;
    const int ty = t >> 4, tx = t & 15;
    float acc[2][2] = {};
    for (int jt = 0; jt < L_; jt += 32) {
        #pragma unroll
        for (int s = 0; s < 4; ++s) {
            int li = t + s * 256;
            int r = li >> 5, c = li & 31;
            int gi = i0 + r, gj = jt + c;
            float av = (gi < L_ && gj < L_) ? Ab[gi * L_ + gj] : 0.f;
            if (gi == gj && gi < L_) av += 1.f;
            As[r][c] = av;
            int gj2 = jt + r, gc = c0 + c;
            float sv = 0.f;
            if (gj2 < L_ && gc < L_) sv = Sb[gj2 * L_ + gc] * dinv_of(db, gj2);
            Ss[r][c] = sv;
        }
        __syncthreads();
        #pragma unroll
        for (int kk = 0; kk < 32; ++kk) {
            float a0 = As[ty*2+0][kk], a1 = As[ty*2+1][kk];
            float2 b = *(const float2*)&Ss[kk][tx * 2];
            acc[0][0] += a0*b.x; acc[0][1] += a0*b.y;
            acc[1][0] += a1*b.x; acc[1][1] += a1*b.y;
        }
        __syncthreads();
    }
    float* Mb = M1 + bh * LL_;
    #pragma unroll
    for (int i = 0; i < 2; ++i) {
        int gi = i0 + ty*2 + i;
        if (gi >= L_) continue;
        float dvi = dinv_of(db, gi);
        #pragma unroll
        for (int j = 0; j < 2; ++j) {
            int gc = c0 + tx*2 + j;
            if (gc < L_) Mb[gi * L_ + gc] = acc[i][j] * dvi;
        }
    }
}

// ---------------------------------------------------------------------------
// K5: sjump = (M1 @ Ahat^T)/sqrt(d);  Ahat[l,j] = dinv_l*(A+I)[l,j]*dinv_j.
// dinv_j folded into B staging, dinv_l and 1/sqrt(d) into epilogue. grid (8,8,8)
__global__ __launch_bounds__(256) void k_sjump(
    const float* __restrict__ M1, const float* __restrict__ A,
    const float* __restrict__ deg, float* __restrict__ attn)
{
    const int bh = blockIdx.z;
    const int i0 = blockIdx.x * 32, l0 = blockIdx.y * 32;
    __shared__ float Ms[32][33];   // M1[i0+r][jt+j]
    __shared__ float Bs[32][33];   // (A+I)[l0+r][jt+j] * dinv_j
    const float* Mb = M1 + bh * LL_;
    const float* Ab = A + bh * LL_;
    const float* db = deg + bh * L_;
    const int t = threadIdx.x;
    const int ty = t >> 4, tx = t & 15;
    float acc[2][2] = {};
    for (int jt = 0; jt < L_; jt += 32) {
        #pragma unroll
        for (int s = 0; s < 4; ++s) {
            int li = t + s * 256;
            int r = li >> 5, c = li & 31;
            int gi = i0 + r, gj = jt + c;
            Ms[r][c] = (gi < L_ && gj < L_) ? Mb[gi * L_ + gj] : 0.f;
            int gl = l0 + r;
            float bv = 0.f;
            if (gl < L_ && gj < L_) {
                bv = Ab[gl * L_ + gj];
                if (gl == gj) bv += 1.f;
                bv *= dinv_of(db, gj);
            }
            Bs[r][c] = bv;
        }
        __syncthreads();
        #pragma unroll
        for (int kk = 0; kk < 32; ++kk) {
            float a0 = Ms[ty*2+0][kk], a1 = Ms[ty*2+1][kk];
            float b0 = Bs[tx*2+0][kk], b1 = Bs[tx*2+1][kk];
            acc[0][0] += a0*b0; acc[0][1] += a0*b1;
            acc[1][0] += a1*b0; acc[1][1] += a1*b1;
        }
        __syncthreads();
    }
    float* ob = attn + bh * LL_;
    #pragma unroll
    for (int i = 0; i < 2; ++i) {
        int gi = i0 + ty*2 + i;
        if (gi >= L_) continue;
        #pragma unroll
        for (int j = 0; j < 2; ++j) {
            int gl = l0 + tx*2 + j;
            if (gl < L_) ob[gi * L_ + gl] = acc[i][j] * dinv_of(db, gl) * INV_SQRT_D;
        }
    }
}

// ---------------------------------------------------------------------------
// K6: softmax + attn@V fused. TI=16 rows/block, grid (15, 8), block 256.
// Softmax kept unnormalized in LDS; 1/sum folded into AV epilogue.
__global__ __launch_bounds__(256) void k_smav(
    const float* __restrict__ sj, const float* __restrict__ v,
    float* __restrict__ oh)
{
    const int bh = blockIdx.y, i0 = blockIdx.x * 16;
    __shared__ float P[16][226];
    __shared__ float rinv[16];
    const float* sb = sj + bh * LL_;
    const float* vb = v + bh * L_ * DH_;
    const int t = threadIdx.x;
    // load 16 rows x 225 cols
    for (int e = t; e < 16 * L_; e += 256) {
        int r = e / L_, c = e - r * L_;
        int gi = i0 + r;
        P[r][c] = (gi < L_) ? sb[gi * L_ + c] : 0.f;
    }
    __syncthreads();
    // softmax: row r handled by 16 lanes (t>>4 == r), lane = t&15
    {
        const int r = t >> 4, lane = t & 15;
        float m = -INFINITY;
        for (int c = lane; c < L_; c += 16) m = fmaxf(m, P[r][c]);
        #pragma unroll
        for (int mk = 1; mk < 16; mk <<= 1) m = fmaxf(m, __shfl_xor(m, mk));
        float ssum = 0.f;
        for (int c = lane; c < L_; c += 16) {
            float e = expf(P[r][c] - m);
            P[r][c] = e;
            ssum += e;
        }
        #pragma unroll
        for (int mk = 1; mk < 16; mk <<= 1) ssum += __shfl_xor(ssum, mk);
        if (lane == 0) rinv[r] = 1.0f / ssum;
    }
    __syncthreads();
    // AV: thread = (dd = t&63, row group rg = t>>6 handles rows rg*4..rg*4+3)
    const int dd = t & 63, rg = t >> 6;
    float acc[4] = {};
    for (int l = 0; l < L_; ++l) {
        float vv = vb[l * DH_ + dd];
        #pragma unroll
        for (int u = 0; u < 4; ++u) acc[u] += P[rg * 4 + u][l] * vv;
    }
    const int b = bh >> 2, h = bh & 3;
    #pragma unroll
    for (int u = 0; u < 4; ++u) {
        int r = rg * 4 + u;
        int gi = i0 + r;
        if (gi < L_) oh[(b * L_ + gi) * (H_ * DH_) + h * DH_ + dd] = acc[u] * rinv[r];
    }
}

// ---------------------------------------------------------------------------
// K7: final = oh @ Wo^T. grid (15,8), block 256
__global__ __launch_bounds__(256) void k_out(
    const float* __restrict__ oh, const float* __restrict__ Wo,
    float* __restrict__ out)
{
    const int m0 = blockIdx.x * 32;
    const int n0 = blockIdx.y * 32;
    __shared__ float Xs[32][36];
    __shared__ float Ws[32][36];
    const int t = threadIdx.x;
    const int ty = t >> 4, tx = t & 15;
    const int sr = t >> 3, sc4 = (t & 7) * 4;
    float acc[2][2] = {};
    for (int kt = 0; kt < D_; kt += 32) {
        int m = m0 + sr;
        float4 xv = (m < M_) ? *(const float4*)&oh[m * D_ + kt + sc4]
                             : make_float4(0.f,0.f,0.f,0.f);
        float4 wv = *(const float4*)&Wo[(n0 + sr) * D_ + kt + sc4];
        *(float4*)&Xs[sr][sc4] = xv;
        *(float4*)&Ws[sr][sc4] = wv;
        __syncthreads();
        #pragma unroll
        for (int kk = 0; kk < 32; ++kk) {
            float a0 = Xs[ty*2+0][kk], a1 = Xs[ty*2+1][kk];
            float b0 = Ws[tx*2+0][kk], b1 = Ws[tx*2+1][kk];
            acc[0][0] += a0*b0; acc[0][1] += a0*b1;
            acc[1][0] += a1*b0; acc[1][1] += a1*b1;
        }
        __syncthreads();
    }
    #pragma unroll
    for (int i = 0; i < 2; ++i) {
        int m = m0 + ty*2 + i;
        if (m >= M_) continue;
        #pragma unroll
        for (int j = 0; j < 2; ++j) {
            int n = n0 + tx*2 + j;
            out[m * D_ + n] = acc[i][j];
        }
    }
}

// ---------------------------------------------------------------------------
extern "C" void kernel_launch(void* const* d_in, const int* in_sizes, int n_in,
                              void* d_out, int out_size, void* d_ws, size_t ws_size,
                              hipStream_t stream)
{
    const float* x  = (const float*)d_in[0];
    const float* Wq = (const float*)d_in[1];
    const float* Wk = (const float*)d_in[2];
    const float* Wv = (const float*)d_in[3];
    const float* Wo = (const float*)d_in[4];
    float* out = (float*)d_out;

    float* ws   = (float*)d_ws;
    float* q    = ws;                  // 115200
    float* k    = q    + B_*H_*L_*DH_; // 115200
    float* v    = k    + B_*H_*L_*DH_; // 115200
    float* S    = v    + B_*H_*L_*DH_; // 405000
    float* A    = S    + BH_*LL_;      // 405000
    float* M1   = A    + BH_*LL_;      // 405000
    float* attn = M1   + BH_*LL_;      // 405000
    float* deg  = attn + BH_*LL_;      // 1800
    float* oh   = deg  + BH_*L_;       // 115200
    // total ~8 MB

    dim3 blk(256);
    k_qkv   <<<dim3(15, 8, 3), blk, 0, stream>>>(x, Wq, Wk, Wv, q, k, v, deg);
    k_scores<<<dim3(8, 8, BH_), blk, 0, stream>>>(q, k, S);
    k_adj   <<<dim3(8, 8, BH_), blk, 0, stream>>>(S, A, deg);
    k_m1    <<<dim3(8, 8, BH_), blk, 0, stream>>>(A, S, deg, M1);
    k_sjump <<<dim3(8, 8, BH_), blk, 0, stream>>>(M1, A, deg, attn);
    k_smav  <<<dim3(15, BH_), blk, 0, stream>>>(attn, v, oh);
    k_out   <<<dim3(15, 8), blk, 0, stream>>>(oh, Wo, out);
}